// Round 5
// baseline (285.481 us; speedup 1.0000x reference)
//
#include <hip/hip_runtime.h>
#include <hip/hip_bf16.h>

#define BB 16
#define NN 1024
#define HH 768
#define NEG_INF_ -9.0e15f
#define SLOPE_ 0.2f

typedef __bf16 bh8 __attribute__((ext_vector_type(8)));
typedef __bf16 bh4 __attribute__((ext_vector_type(4)));
typedef float f4 __attribute__((ext_vector_type(4)));
typedef unsigned int u32;
typedef unsigned long long u64;

// ---------------- wave-level reductions ----------------

__device__ __forceinline__ float wave_sum0(float v) {       // result valid in lane 0
    #pragma unroll
    for (int off = 32; off > 0; off >>= 1) v += __shfl_down(v, off, 64);
    return v;
}
__device__ __forceinline__ float wave_sum_all(float v) {
    #pragma unroll
    for (int off = 1; off < 64; off <<= 1) v += __shfl_xor(v, off, 64);
    return v;
}
__device__ __forceinline__ float wave_max_all(float v) {
    #pragma unroll
    for (int off = 1; off < 64; off <<= 1) v = fmaxf(v, __shfl_xor(v, off, 64));
    return v;
}

// ---------------- async global->LDS 16B ----------------

__device__ __forceinline__ void gl_lds16(const void* g, void* l) {
    __builtin_amdgcn_global_load_lds(
        (const __attribute__((address_space(1))) u32*)g,
        (__attribute__((address_space(3))) u32*)l, 16, 0, 0);
}

// ---------------- kernel 1: wa = W @ a1|a2 (one wave per f) + zero-init t ----------------
// grid 192 x 256

__global__ __launch_bounds__(256) void wa_kernel(const float* __restrict__ W,
                                                 const float* __restrict__ a,
                                                 float* __restrict__ wa1,
                                                 float* __restrict__ wa2,
                                                 float* __restrict__ t1,
                                                 float* __restrict__ t2) {
    const int gid = blockIdx.x * 256 + threadIdx.x;
    if (gid < BB * NN) { t1[gid] = 0.f; t2[gid] = 0.f; }   // d_ws is poisoned; xt accumulates

    const int f = blockIdx.x * 4 + (threadIdx.x >> 6);
    const int lane = threadIdx.x & 63;
    const float* Wr = W + (size_t)f * HH;
    float v1 = 0.f, v2 = 0.f;
    #pragma unroll
    for (int i = 0; i < 3; i++) {
        const int h = lane * 4 + i * 256;
        const float4 w  = *(const float4*)(Wr + h);
        const float4 a1 = *(const float4*)(a + h);
        const float4 a2 = *(const float4*)(a + HH + h);
        v1 += w.x * a1.x + w.y * a1.y + w.z * a1.z + w.w * a1.w;
        v2 += w.x * a2.x + w.y * a2.y + w.z * a2.z + w.w * a2.w;
    }
    v1 = wave_sum0(v1);
    v2 = wave_sum0(v2);
    if (lane == 0) { wa1[f] = v1; wa2[f] = v2; }
}

// ---------------- kernel 2: xT transpose (f32->bf16) FUSED with t partial dots ----------------
// grid (24 htiles, 32 ntiles, BB) x 256; 32x32 tiles

__global__ __launch_bounds__(256) void xt_kernel(const float* __restrict__ x,
                                                 const float* __restrict__ wa1,
                                                 const float* __restrict__ wa2,
                                                 __bf16* __restrict__ xT,
                                                 float* __restrict__ t1,
                                                 float* __restrict__ t2) {
    __shared__ __bf16 T[32][36];
    const int b = blockIdx.z, nt = blockIdx.y, ht = blockIdx.x;
    const int t = threadIdx.x;
    const int r = t >> 3;          // n within tile (0..31)
    const int c = (t & 7) * 4;     // h within tile (0..28)
    const float4 v = *(const float4*)(x + ((size_t)b * NN + nt * 32 + r) * HH + ht * 32 + c);
    T[r][c + 0] = (__bf16)v.x; T[r][c + 1] = (__bf16)v.y;
    T[r][c + 2] = (__bf16)v.z; T[r][c + 3] = (__bf16)v.w;

    // t partial: dot of this row-segment with wa (wa is 3KB -> L1/L2 resident)
    const float4 w1 = *(const float4*)(wa1 + ht * 32 + c);
    const float4 w2 = *(const float4*)(wa2 + ht * 32 + c);
    float p1 = v.x * w1.x + v.y * w1.y + v.z * w1.z + v.w * w1.w;
    float p2 = v.x * w2.x + v.y * w2.y + v.z * w2.z + v.w * w2.w;
    // 8 threads per row are consecutive lanes -> width-8 shuffle reduce
    p1 += __shfl_down(p1, 4, 8); p1 += __shfl_down(p1, 2, 8); p1 += __shfl_down(p1, 1, 8);
    p2 += __shfl_down(p2, 4, 8); p2 += __shfl_down(p2, 2, 8); p2 += __shfl_down(p2, 1, 8);
    if ((t & 7) == 0) {
        atomicAdd(&t1[b * NN + nt * 32 + r], p1);
        atomicAdd(&t2[b * NN + nt * 32 + r], p2);
    }

    __syncthreads();
    const int h = t >> 3;          // h within tile
    const int nc = (t & 7) * 4;    // n within tile
    bh4 o = { T[nc + 0][h], T[nc + 1][h], T[nc + 2][h], T[nc + 3][h] };
    *(bh4*)(xT + ((size_t)b * HH + ht * 32 + h) * NN + nt * 32 + nc) = o;
}

// ---------------- kernel 3: s = adj·t + adj->bf16 (exact) + pack bits ----------------
// grid 4096 x 256 (one wave per row)

__global__ __launch_bounds__(256) void s_pack_kernel(const float* __restrict__ adj,
                                                     const float* __restrict__ t1,
                                                     const float* __restrict__ t2,
                                                     float* __restrict__ s1,
                                                     float* __restrict__ s2,
                                                     __bf16* __restrict__ adjB,
                                                     u64* __restrict__ bits) {
    const int row = blockIdx.x * 4 + (threadIdx.x >> 6);
    const int lane = threadIdx.x & 63;
    const int b = row >> 10;
    const float* ar = adj + (size_t)row * NN;
    __bf16* abr = adjB + (size_t)row * NN;
    const float* t1b = t1 + b * NN;
    const float* t2b = t2 + b * NN;
    float v1 = 0.f, v2 = 0.f;
    u64 myw = 0;
    #pragma unroll
    for (int i = 0; i < 4; i++) {
        const int j = lane * 4 + i * 256;
        const float4 av = *(const float4*)(ar + j);
        const float4 u  = *(const float4*)(t1b + j);
        const float4 w  = *(const float4*)(t2b + j);
        v1 += av.x * u.x + av.y * u.y + av.z * u.z + av.w * u.w;
        v2 += av.x * w.x + av.y * w.y + av.z * w.z + av.w * w.w;
        bh4 o = { (__bf16)av.x, (__bf16)av.y, (__bf16)av.z, (__bf16)av.w };  // 0/1 exact
        *(bh4*)(abr + j) = o;
        // word (i*4+e), bit 'lane' = adj[row][lane*4+e+i*256] > eps  (strided semantics,
        // softmax uses the identical (i,e,lane) mapping)
        const u64 b0 = __ballot(av.x > 1e-6f);
        const u64 b1 = __ballot(av.y > 1e-6f);
        const u64 b2 = __ballot(av.z > 1e-6f);
        const u64 b3 = __ballot(av.w > 1e-6f);
        if (lane == i * 4 + 0) myw = b0;
        if (lane == i * 4 + 1) myw = b1;
        if (lane == i * 4 + 2) myw = b2;
        if (lane == i * 4 + 3) myw = b3;
    }
    v1 = wave_sum0(v1);
    v2 = wave_sum0(v2);
    if (lane == 0) { s1[row] = v1; s2[row] = v2; }
    if (lane < 16) bits[(size_t)row * 16 + lane] = myw;
}

// ---------------- kernel 4: node_vec = adjB @ xT^T, bf16 MFMA, BK=64 XOR-swizzled ----------------
// grid (6,8,BB) x 256; 128x128 tile. LDS layout: slot (r,j) holds global chunk (r, j^(r&7)),
// so gl_lds16's fixed dest (base+lane*16) realizes a swizzle that spreads fragment reads
// across all 32 banks (row stride 128B would otherwise alias all rows to the same banks).

__global__ __launch_bounds__(256) void gemm_bf16(const __bf16* __restrict__ adjB,
                                                 const __bf16* __restrict__ xT,
                                                 float* __restrict__ out) {
    __shared__ __bf16 As[128 * 64];   // 16 KB
    __shared__ __bf16 Bs[128 * 64];   // 16 KB
    const int b = blockIdx.z, bm = blockIdx.y, bn = blockIdx.x;
    const int tid = threadIdx.x, lane = tid & 63, wave = tid >> 6;
    const int wr = (wave >> 1) << 6;
    const int wc = (wave & 1) << 6;
    const int quad = lane >> 4, l16 = lane & 15;

    const __bf16* Ab = adjB + ((size_t)b * NN + bm * 128) * NN;
    const __bf16* Xb = xT + ((size_t)b * HH + bn * 128) * NN;

    f4 acc[4][4];
    #pragma unroll
    for (int i = 0; i < 4; i++)
        #pragma unroll
        for (int j = 0; j < 4; j++)
            acc[i][j] = (f4){0.f, 0.f, 0.f, 0.f};

    for (int kt = 0; kt < NN; kt += 64) {
        #pragma unroll
        for (int it = 0; it < 4; it++) {
            const int c = tid + 256 * it;     // LDS 16B-slot index; byte addr = c*16 = base+lane*16
            const int r = c >> 3;             // row 0..127
            const int j = c & 7;              // LDS chunk within row
            const int kc = j ^ (r & 7);       // global k-chunk (swizzle)
            gl_lds16(Ab + (size_t)r * NN + kt + kc * 8, &As[r * 64 + j * 8]);
            gl_lds16(Xb + (size_t)r * NN + kt + kc * 8, &Bs[r * 64 + j * 8]);
        }
        __syncthreads();   // drains vmcnt(0): tiles ready

        #pragma unroll
        for (int s = 0; s < 2; s++) {
            bh8 af[4], bf_[4];
            #pragma unroll
            for (int i = 0; i < 4; i++) {
                const int row = wr + i * 16 + l16;
                const int jj = (s * 4 + quad) ^ (row & 7);
                af[i] = *(const bh8*)&As[row * 64 + jj * 8];
            }
            #pragma unroll
            for (int j = 0; j < 4; j++) {
                const int row = wc + j * 16 + l16;
                const int jj = (s * 4 + quad) ^ (row & 7);
                bf_[j] = *(const bh8*)&Bs[row * 64 + jj * 8];
            }
            #pragma unroll
            for (int i = 0; i < 4; i++)
                #pragma unroll
                for (int j = 0; j < 4; j++)
                    acc[i][j] = __builtin_amdgcn_mfma_f32_16x16x32_bf16(af[i], bf_[j], acc[i][j], 0, 0, 0);
        }
        __syncthreads();   // reads done before next staging overwrites
    }

    // epilogue: C/D layout col = lane&15, row = (lane>>4)*4 + reg  [m89-verified]
    float* Cb = out + (size_t)b * NN * HH + (size_t)bm * 128 * HH + bn * 128;
    const int rbase = wr + quad * 4;
    const int cbase = wc + l16;
    #pragma unroll
    for (int i = 0; i < 4; i++)
        #pragma unroll
        for (int j = 0; j < 4; j++)
            #pragma unroll
            for (int r = 0; r < 4; r++)
                Cb[(size_t)(rbase + i * 16 + r) * HH + cbase + j * 16] = acc[i][j][r];
}

// ---------------- kernel 5: softmax -- one wave per row, mask from bits (in d_ws: no race) ----------------
// grid 4096 x 256

__global__ __launch_bounds__(256) void softmax_kernel(const u64* __restrict__ bits,
                                                      const float* __restrict__ nl,
                                                      const float* __restrict__ s1,
                                                      const float* __restrict__ s2,
                                                      float* __restrict__ attn) {
    const int row = blockIdx.x * 4 + (threadIdx.x >> 6);
    const int lane = threadIdx.x & 63;
    const int b = row >> 10, n = row & (NN - 1);
    const u64* bwr = bits + (size_t)row * 16;
    const float* nlb = nl + (size_t)b * NN;
    const float* s2b = s2 + (size_t)b * NN;
    const float s1v = s1[row];
    const bool rowok = nlb[n] > 1e-6f;

    f4 sc[4];
    float mx = NEG_INF_;
    #pragma unroll
    for (int i = 0; i < 4; i++) {
        const int j = lane * 4 + i * 256;
        const float4 sv = *(const float4*)(s2b + j);
        const float4 nv = *(const float4*)(nlb + j);
        const u64 w0 = bwr[i * 4 + 0], w1 = bwr[i * 4 + 1];
        const u64 w2 = bwr[i * 4 + 2], w3 = bwr[i * 4 + 3];
        const float zs[4] = { s1v + sv.x, s1v + sv.y, s1v + sv.z, s1v + sv.w };
        const float ns[4] = { nv.x, nv.y, nv.z, nv.w };
        const bool ab[4] = { (bool)((w0 >> lane) & 1ull), (bool)((w1 >> lane) & 1ull),
                             (bool)((w2 >> lane) & 1ull), (bool)((w3 >> lane) & 1ull) };
        #pragma unroll
        for (int e = 0; e < 4; e++) {
            const float z = zs[e];
            const float lr = z > 0.f ? z : SLOPE_ * z;
            const bool valid = rowok && ab[e] && (ns[e] > 1e-6f);
            sc[i][e] = valid ? lr : NEG_INF_;
            mx = fmaxf(mx, sc[i][e]);
        }
    }
    mx = wave_max_all(mx);

    f4 ex[4];
    float sum = 0.f;
    #pragma unroll
    for (int i = 0; i < 4; i++)
        #pragma unroll
        for (int e = 0; e < 4; e++) {
            ex[i][e] = __expf(sc[i][e] - mx);   // all-masked row -> uniform, matches JAX
            sum += ex[i][e];
        }
    sum = wave_sum_all(sum);
    const float inv = 1.0f / sum;

    float* outr = attn + (size_t)row * NN;
    #pragma unroll
    for (int i = 0; i < 4; i++) {
        const int j = lane * 4 + i * 256;
        float4 o;
        o.x = ex[i][0] * inv; o.y = ex[i][1] * inv;
        o.z = ex[i][2] * inv; o.w = ex[i][3] * inv;
        *(float4*)(outr + j) = o;
    }
}

// ---------------- launch ----------------

extern "C" void kernel_launch(void* const* d_in, const int* in_sizes, int n_in,
                              void* d_out, int out_size, void* d_ws, size_t ws_size,
                              hipStream_t stream) {
    const float* x   = (const float*)d_in[0];   // (16,1024,768)
    const float* nl  = (const float*)d_in[1];   // (16,1024)
    const float* adj = (const float*)d_in[2];   // (16,1024,1024)
    const float* W   = (const float*)d_in[3];   // (768,768)
    const float* a   = (const float*)d_in[4];   // (1536,1)

    float* out = (float*)d_out;
    float* node_vec = out;                               // 16*1024*768 floats
    float* attn = out + (size_t)BB * NN * HH;            // 16*1024*1024 floats

    // ALL scratch in d_ws (ws_size ~448 MiB per the harness fill; we use ~59 MB):
    char* wsb = (char*)d_ws;
    float* wa1 = (float*)(wsb);                          // 3 KB
    float* wa2 = wa1 + HH;
    float* t1  = wa2 + HH;                               // 64 KB each
    float* t2  = t1 + BB * NN;
    float* s1  = t2 + BB * NN;
    float* s2  = s1 + BB * NN;
    u64*    bits = (u64*)(wsb + (1u << 20));             // 2 MB   @ 1 MB
    __bf16* xT   = (__bf16*)(wsb + (4u << 20));          // 24 MB  @ 4 MB
    __bf16* adjB = (__bf16*)(wsb + (28u << 20));         // 32 MB  @ 28 MB

    hipLaunchKernelGGL(wa_kernel, dim3(192), dim3(256), 0, stream, W, a, wa1, wa2, t1, t2);
    hipLaunchKernelGGL(xt_kernel, dim3(24, 32, BB), dim3(256), 0, stream, x, wa1, wa2, xT, t1, t2);
    hipLaunchKernelGGL(s_pack_kernel, dim3(4096), dim3(256), 0, stream, adj, t1, t2, s1, s2, adjB, bits);
    hipLaunchKernelGGL(gemm_bf16, dim3(6, 8, BB), dim3(256), 0, stream, adjB, xT, node_vec);
    hipLaunchKernelGGL(softmax_kernel, dim3(4096), dim3(256), 0, stream, bits, nl, s1, s2, attn);
}

// Round 6
// 266.255 us; speedup vs baseline: 1.0722x; 1.0722x over previous
//
#include <hip/hip_runtime.h>
#include <hip/hip_bf16.h>

#define BB 16
#define NN 1024
#define HH 768
#define NEG_INF_ -9.0e15f
#define SLOPE_ 0.2f

typedef __bf16 bh8 __attribute__((ext_vector_type(8)));
typedef __bf16 bh4 __attribute__((ext_vector_type(4)));
typedef float f4 __attribute__((ext_vector_type(4)));
typedef unsigned int u32;
typedef unsigned long long u64;

// ---------------- wave-level reductions ----------------

__device__ __forceinline__ float wave_sum0(float v) {       // result valid in lane 0
    #pragma unroll
    for (int off = 32; off > 0; off >>= 1) v += __shfl_down(v, off, 64);
    return v;
}
__device__ __forceinline__ float wave_sum_all(float v) {
    #pragma unroll
    for (int off = 1; off < 64; off <<= 1) v += __shfl_xor(v, off, 64);
    return v;
}
__device__ __forceinline__ float wave_max_all(float v) {
    #pragma unroll
    for (int off = 1; off < 64; off <<= 1) v = fmaxf(v, __shfl_xor(v, off, 64));
    return v;
}

// ---------------- async global->LDS 16B ----------------

__device__ __forceinline__ void gl_lds16(const void* g, void* l) {
    __builtin_amdgcn_global_load_lds(
        (const __attribute__((address_space(1))) u32*)g,
        (__attribute__((address_space(3))) u32*)l, 16, 0, 0);
}

// ---------------- kernel 1: wa = W @ a1|a2 (one wave per f) + zero-init t ----------------
// grid 192 x 256

__global__ __launch_bounds__(256) void wa_kernel(const float* __restrict__ W,
                                                 const float* __restrict__ a,
                                                 float* __restrict__ wa1,
                                                 float* __restrict__ wa2,
                                                 float* __restrict__ t1,
                                                 float* __restrict__ t2) {
    const int gid = blockIdx.x * 256 + threadIdx.x;
    if (gid < BB * NN) { t1[gid] = 0.f; t2[gid] = 0.f; }   // d_ws is poisoned; xt accumulates

    const int f = blockIdx.x * 4 + (threadIdx.x >> 6);
    const int lane = threadIdx.x & 63;
    const float* Wr = W + (size_t)f * HH;
    float v1 = 0.f, v2 = 0.f;
    #pragma unroll
    for (int i = 0; i < 3; i++) {
        const int h = lane * 4 + i * 256;
        const float4 w  = *(const float4*)(Wr + h);
        const float4 a1 = *(const float4*)(a + h);
        const float4 a2 = *(const float4*)(a + HH + h);
        v1 += w.x * a1.x + w.y * a1.y + w.z * a1.z + w.w * a1.w;
        v2 += w.x * a2.x + w.y * a2.y + w.z * a2.z + w.w * a2.w;
    }
    v1 = wave_sum0(v1);
    v2 = wave_sum0(v2);
    if (lane == 0) { wa1[f] = v1; wa2[f] = v2; }
}

// ---------------- kernel 2: xT transpose (f32->bf16) FUSED with t partial dots ----------------
// grid (24 htiles, 32 ntiles, BB) x 256; 32x32 tiles

__global__ __launch_bounds__(256) void xt_kernel(const float* __restrict__ x,
                                                 const float* __restrict__ wa1,
                                                 const float* __restrict__ wa2,
                                                 __bf16* __restrict__ xT,
                                                 float* __restrict__ t1,
                                                 float* __restrict__ t2) {
    __shared__ __bf16 T[32][36];
    const int b = blockIdx.z, nt = blockIdx.y, ht = blockIdx.x;
    const int t = threadIdx.x;
    const int r = t >> 3;          // n within tile (0..31)
    const int c = (t & 7) * 4;     // h within tile (0..28)
    const float4 v = *(const float4*)(x + ((size_t)b * NN + nt * 32 + r) * HH + ht * 32 + c);
    T[r][c + 0] = (__bf16)v.x; T[r][c + 1] = (__bf16)v.y;
    T[r][c + 2] = (__bf16)v.z; T[r][c + 3] = (__bf16)v.w;

    // t partial: dot of this row-segment with wa (wa is 3KB -> L1/L2 resident)
    const float4 w1 = *(const float4*)(wa1 + ht * 32 + c);
    const float4 w2 = *(const float4*)(wa2 + ht * 32 + c);
    float p1 = v.x * w1.x + v.y * w1.y + v.z * w1.z + v.w * w1.w;
    float p2 = v.x * w2.x + v.y * w2.y + v.z * w2.z + v.w * w2.w;
    // 8 threads per row are consecutive lanes -> width-8 shuffle reduce
    p1 += __shfl_down(p1, 4, 8); p1 += __shfl_down(p1, 2, 8); p1 += __shfl_down(p1, 1, 8);
    p2 += __shfl_down(p2, 4, 8); p2 += __shfl_down(p2, 2, 8); p2 += __shfl_down(p2, 1, 8);
    if ((t & 7) == 0) {
        atomicAdd(&t1[b * NN + nt * 32 + r], p1);
        atomicAdd(&t2[b * NN + nt * 32 + r], p2);
    }

    __syncthreads();
    const int h = t >> 3;          // h within tile
    const int nc = (t & 7) * 4;    // n within tile
    bh4 o = { T[nc + 0][h], T[nc + 1][h], T[nc + 2][h], T[nc + 3][h] };
    *(bh4*)(xT + ((size_t)b * HH + ht * 32 + h) * NN + nt * 32 + nc) = o;
}

// ---------------- kernel 3: s = adj·t + pack adj bits (LINEAR layout, R2-verified) ----------------
// grid 4096 x 256 (one wave per row). bits[row][w] bit b = adj[row][w*64+b] > eps.

__global__ __launch_bounds__(256) void s_pack_kernel(const float* __restrict__ adj,
                                                     const float* __restrict__ t1,
                                                     const float* __restrict__ t2,
                                                     float* __restrict__ s1,
                                                     float* __restrict__ s2,
                                                     u64* __restrict__ bits) {
    const int row = blockIdx.x * 4 + (threadIdx.x >> 6);
    const int lane = threadIdx.x & 63;
    const int b = row >> 10;
    const float* ar = adj + (size_t)row * NN;
    const float* t1b = t1 + b * NN;
    const float* t2b = t2 + b * NN;
    float v1 = 0.f, v2 = 0.f;
    u64 myw = 0;
    #pragma unroll
    for (int i = 0; i < 16; i++) {
        const int j = lane + 64 * i;           // column; word i, bit lane  (linear)
        const float av = ar[j];
        v1 += av * t1b[j];
        v2 += av * t2b[j];
        const u64 bal = __ballot(av > 1e-6f);
        if (lane == i) myw = bal;
    }
    v1 = wave_sum0(v1);
    v2 = wave_sum0(v2);
    if (lane == 0) { s1[row] = v1; s2[row] = v2; }
    if (lane < 16) bits[(size_t)row * 16 + lane] = myw;
}

// ---------------- kernel 4: node_vec = adj @ x via bits-A (LDS LUT) + bf16-B MFMA ----------------
// grid (6,8,BB) x 256. A-bits (16 KB) loaded once, expanded per-frag through a 256-entry LUT
// (adj ~5.6% dense -> ~63% of bytes are 0 -> LUT reads mostly broadcast). B staged per-iter
// via global_load_lds w/ XOR swizzle (slot (r,j) holds global chunk j^(r&7), R5-verified).

#define BW 17   // u64 words per bits row in LDS: banks (2r+2w)%32 distinct across l16 -> conflict-free

__global__ __launch_bounds__(256) void gemm_bits(const u64* __restrict__ bits,
                                                 const __bf16* __restrict__ xT,
                                                 float* __restrict__ out) {
    __shared__ __bf16 LUT[256 * 8];       // 4 KB:   LUT[b][j] = (b>>j)&1
    __shared__ u64 bitsL[128 * BW];       // 17.4 KB
    __shared__ __bf16 Bs[128 * 64];       // 16 KB
    const int b = blockIdx.z, bm = blockIdx.y, bn = blockIdx.x;
    const int tid = threadIdx.x, lane = tid & 63, wave = tid >> 6;
    const int wr = (wave >> 1) << 6;
    const int wc = (wave & 1) << 6;
    const int quad = lane >> 4, l16 = lane & 15;

    // build LUT (one entry per thread)
    {
        bh8 e;
        #pragma unroll
        for (int j = 0; j < 8; j++) e[j] = ((tid >> j) & 1) ? (__bf16)1.0f : (__bf16)0.0f;
        *(bh8*)&LUT[tid * 8] = e;
    }
    // load A bitmask rows bm*128..+128 (16 KB contiguous), once
    {
        const u64* bg = bits + ((size_t)b * NN + bm * 128) * 16;
        #pragma unroll
        for (int q = 0; q < 8; q++) {
            const int g = tid * 8 + q;                 // global word index
            bitsL[(g >> 4) * BW + (g & 15)] = bg[g];
        }
    }

    const __bf16* Xb = xT + ((size_t)b * HH + bn * 128) * NN;

    f4 acc[4][4];
    #pragma unroll
    for (int i = 0; i < 4; i++)
        #pragma unroll
        for (int j = 0; j < 4; j++)
            acc[i][j] = (f4){0.f, 0.f, 0.f, 0.f};

    __syncthreads();   // LUT + bits visible

    for (int kt = 0; kt < NN; kt += 64) {
        // stage B only: Bs slot (r,j) <- global chunk j^(r&7)
        #pragma unroll
        for (int it = 0; it < 4; it++) {
            const int c = tid + 256 * it;
            const int r = c >> 3, j = c & 7, kc = j ^ (r & 7);
            gl_lds16(Xb + (size_t)r * NN + kt + kc * 8, &Bs[r * 64 + j * 8]);
        }
        __syncthreads();   // drains vmcnt(0): B tile ready

        const int w = kt >> 6;
        u64 aw[4];
        #pragma unroll
        for (int i = 0; i < 4; i++)
            aw[i] = bitsL[(wr + i * 16 + l16) * BW + w];   // broadcast across quads, CF

        #pragma unroll
        for (int s = 0; s < 2; s++) {
            bh8 af[4], bf_[4];
            #pragma unroll
            for (int i = 0; i < 4; i++) {
                const u32 byte = (u32)(aw[i] >> ((s * 4 + quad) * 8)) & 0xffu;
                af[i] = *(const bh8*)&LUT[byte * 8];       // k = kt + (s*4+quad)*8 + 0..7
            }
            #pragma unroll
            for (int j = 0; j < 4; j++) {
                const int row = wc + j * 16 + l16;
                const int jj = (s * 4 + quad) ^ (row & 7);
                bf_[j] = *(const bh8*)&Bs[row * 64 + jj * 8];   // same k-chunk s*4+quad
            }
            #pragma unroll
            for (int i = 0; i < 4; i++)
                #pragma unroll
                for (int j = 0; j < 4; j++)
                    acc[i][j] = __builtin_amdgcn_mfma_f32_16x16x32_bf16(af[i], bf_[j], acc[i][j], 0, 0, 0);
        }
        __syncthreads();   // reads done before next staging overwrites Bs
    }

    // epilogue: C/D layout col = lane&15, row = (lane>>4)*4 + reg  [m89-verified]
    float* Cb = out + (size_t)b * NN * HH + (size_t)bm * 128 * HH + bn * 128;
    const int rbase = wr + quad * 4;
    const int cbase = wc + l16;
    #pragma unroll
    for (int i = 0; i < 4; i++)
        #pragma unroll
        for (int j = 0; j < 4; j++)
            #pragma unroll
            for (int r = 0; r < 4; r++)
                Cb[(size_t)(rbase + i * 16 + r) * HH + cbase + j * 16] = acc[i][j][r];
}

// ---------------- kernel 5: softmax -- one wave per row, mask from linear bits ----------------
// grid 4096 x 256. element j = lane*4 + i*256 + e -> word i*4+(lane>>4), bit (lane&15)*4+e.

__global__ __launch_bounds__(256) void softmax_kernel(const u64* __restrict__ bits,
                                                      const float* __restrict__ nl,
                                                      const float* __restrict__ s1,
                                                      const float* __restrict__ s2,
                                                      float* __restrict__ attn) {
    const int row = blockIdx.x * 4 + (threadIdx.x >> 6);
    const int lane = threadIdx.x & 63;
    const int b = row >> 10, n = row & (NN - 1);
    const u64* bwr = bits + (size_t)row * 16;
    const float* nlb = nl + (size_t)b * NN;
    const float* s2b = s2 + (size_t)b * NN;
    const float s1v = s1[row];
    const bool rowok = nlb[n] > 1e-6f;
    const int bitbase = (lane & 15) * 4;

    f4 sc[4];
    float mx = NEG_INF_;
    #pragma unroll
    for (int i = 0; i < 4; i++) {
        const int j = lane * 4 + i * 256;
        const float4 sv = *(const float4*)(s2b + j);
        const float4 nv = *(const float4*)(nlb + j);
        const u64 w64 = bwr[i * 4 + (lane >> 4)];
        const float zs[4] = { s1v + sv.x, s1v + sv.y, s1v + sv.z, s1v + sv.w };
        const float ns[4] = { nv.x, nv.y, nv.z, nv.w };
        #pragma unroll
        for (int e = 0; e < 4; e++) {
            const float z = zs[e];
            const float lr = z > 0.f ? z : SLOPE_ * z;
            const bool valid = rowok && ((w64 >> (bitbase + e)) & 1ull) && (ns[e] > 1e-6f);
            sc[i][e] = valid ? lr : NEG_INF_;
            mx = fmaxf(mx, sc[i][e]);
        }
    }
    mx = wave_max_all(mx);

    f4 ex[4];
    float sum = 0.f;
    #pragma unroll
    for (int i = 0; i < 4; i++)
        #pragma unroll
        for (int e = 0; e < 4; e++) {
            ex[i][e] = __expf(sc[i][e] - mx);   // all-masked row -> uniform, matches JAX
            sum += ex[i][e];
        }
    sum = wave_sum_all(sum);
    const float inv = 1.0f / sum;

    float* outr = attn + (size_t)row * NN;
    #pragma unroll
    for (int i = 0; i < 4; i++) {
        const int j = lane * 4 + i * 256;
        float4 o;
        o.x = ex[i][0] * inv; o.y = ex[i][1] * inv;
        o.z = ex[i][2] * inv; o.w = ex[i][3] * inv;
        *(float4*)(outr + j) = o;
    }
}

// ---------------- launch ----------------

extern "C" void kernel_launch(void* const* d_in, const int* in_sizes, int n_in,
                              void* d_out, int out_size, void* d_ws, size_t ws_size,
                              hipStream_t stream) {
    const float* x   = (const float*)d_in[0];   // (16,1024,768)
    const float* nl  = (const float*)d_in[1];   // (16,1024)
    const float* adj = (const float*)d_in[2];   // (16,1024,1024)
    const float* W   = (const float*)d_in[3];   // (768,768)
    const float* a   = (const float*)d_in[4];   // (1536,1)

    float* out = (float*)d_out;
    float* node_vec = out;                               // 16*1024*768 floats
    float* attn = out + (size_t)BB * NN * HH;            // 16*1024*1024 floats

    // ALL scratch in d_ws (~448 MiB; we use ~28 MB):
    char* wsb = (char*)d_ws;
    float* wa1 = (float*)(wsb);                          // 3 KB
    float* wa2 = wa1 + HH;
    float* t1  = wa2 + HH;                               // 64 KB each
    float* t2  = t1 + BB * NN;
    float* s1  = t2 + BB * NN;
    float* s2  = s1 + BB * NN;
    u64*    bits = (u64*)(wsb + (1u << 20));             // 2 MB   @ 1 MB
    __bf16* xT   = (__bf16*)(wsb + (4u << 20));          // 24 MB  @ 4 MB

    hipLaunchKernelGGL(wa_kernel, dim3(192), dim3(256), 0, stream, W, a, wa1, wa2, t1, t2);
    hipLaunchKernelGGL(xt_kernel, dim3(24, 32, BB), dim3(256), 0, stream, x, wa1, wa2, xT, t1, t2);
    hipLaunchKernelGGL(s_pack_kernel, dim3(4096), dim3(256), 0, stream, adj, t1, t2, s1, s2, bits);
    hipLaunchKernelGGL(gemm_bits, dim3(6, 8, BB), dim3(256), 0, stream, bits, xT, node_vec);
    hipLaunchKernelGGL(softmax_kernel, dim3(4096), dim3(256), 0, stream, bits, nl, s1, s2, attn);
}